// Round 1
// baseline (233.980 us; speedup 1.0000x reference)
//
#include <hip/hip_runtime.h>
#include <hip/hip_bf16.h>
#include <cmath>

// Problem constants (fixed by setup_inputs)
#define H_DIM 1024
#define W_DIM 64
#define N_BATCH 2
#define DCH 32
#define WINR 32
#define TQ 256                    // queries per block
#define HALO (TQ + 2*WINR)        // 320 staged positions (queries + halo)
#define NROW (N_BATCH * W_DIM)    // 128 attention rows

__device__ __forceinline__ float gelu_f(float v) {
    // exact GELU: 0.5*v*(1+erf(v/sqrt(2)))
    return 0.5f * v * (1.0f + erff(v * 0.70710678118654752440f));
}

// ---------------------------------------------------------------- K0: zero accumulators
__global__ void k_init(double* __restrict__ acc) {
    int t = threadIdx.x;
    if (t < 8) acc[t] = 0.0;
}

// ---------------------------------------------------------------- K1: per-batch sum / sumsq of x
// GN1 trick: feat = x * w_in[d] (C==1), so GN1 stats derive from Sx, Sx2 only.
__global__ __launch_bounds__(256) void k_xstats(const float* __restrict__ x,
                                                double* __restrict__ acc) {
    const int b = blockIdx.x;          // 128 blocks, 1024 contiguous floats each
    const int t = threadIdx.x;
    float4 v = ((const float4*)(x + (size_t)b * 1024))[t];
    double s  = (double)v.x + (double)v.y + (double)v.z + (double)v.w;
    double s2 = (double)v.x*(double)v.x + (double)v.y*(double)v.y +
                (double)v.z*(double)v.z + (double)v.w*(double)v.w;
    #pragma unroll
    for (int o = 32; o; o >>= 1) {
        s  += __shfl_down(s, o);
        s2 += __shfl_down(s2, o);
    }
    if ((t & 63) == 0) {
        const int batch = b >> 6;      // 64 blocks per batch
        atomicAdd(&acc[batch*2 + 0], s);
        atomicAdd(&acc[batch*2 + 1], s2);
    }
}

// ---------------------------------------------------------------- K2: fused z -> QKV -> banded attention -> residual
// grid = 128 rows * 4 tiles = 512 blocks, 256 threads (thread == query within tile)
__global__ __launch_bounds__(256) void k_main(
    const float* __restrict__ x,
    const float* __restrict__ w_in,
    const float* __restrict__ w_q,
    const float* __restrict__ w_k,
    const float* __restrict__ w_v,
    const float* __restrict__ gn_w,
    const float* __restrict__ gn_b,
    const float* __restrict__ gammap,
    const double* __restrict__ stats,     // [0..3] = Sx,Sx2 per batch
    double* __restrict__ gn2acc,          // [0..3] = GN2 sums per batch
    float* __restrict__ out_pre)          // [128][1024][32] pixel-major
{
    // XOR-swizzled (float4-chunk granularity, by p&7) LDS tiles: conflict-free
    // for both row-broadcast reads (proj) and lane-per-row reads (attention).
    __shared__ float zs[HALO * DCH];     // 40 KB
    __shared__ float ks[HALO * DCH];     // 40 KB
    __shared__ float vs[HALO * DCH];     // 40 KB

    const int t    = threadIdx.x;
    const int bid  = blockIdx.x;
    const int row  = bid >> 2;           // 0..127  (= b*64 + w)
    const int tile = bid & 3;
    const int batch = row >> 6;
    const int h0 = tile * TQ;            // first query of tile
    const int g0 = h0 - WINR;            // global h of local halo slot p=0

    // ---- GN1 statistics from x sums (C==1 algebra) ----
    const double Sx  = stats[batch*2 + 0];
    const double Sx2 = stats[batch*2 + 1];
    float sw = 0.f, sw2 = 0.f;
    #pragma unroll
    for (int d = 0; d < DCH; ++d) { float w = w_in[d]; sw += w; sw2 += w*w; }
    const double n1   = (double)DCH * W_DIM * H_DIM;         // 2097152
    const double mu1d = (double)sw  * Sx  / n1;
    const double ex2  = (double)sw2 * Sx2 / n1;
    const double var1 = ex2 - mu1d*mu1d;
    const float mu1   = (float)mu1d;
    const float rstd1 = (float)(1.0 / sqrt(var1 + 1e-5));

    const float* xrow = x + (size_t)row * H_DIM;

    // ---- Phase A: stage z = gelu(GN1(x*w_in)) for all 320 halo positions ----
    #pragma unroll 4
    for (int rep = 0; rep < (HALO * DCH) / 256; ++rep) {     // 40 reps
        int idx = rep * 256 + t;
        int p = idx >> 5;
        int d = idx & 31;
        int h = g0 + p;
        float xv = ((unsigned)h < H_DIM) ? xrow[h] : 0.f;
        float feat = xv * w_in[d];
        float zv = gelu_f((feat - mu1) * rstd1 * gn_w[d] + gn_b[d]);
        int cp = (d >> 2) ^ (p & 7);
        zs[p * DCH + cp * 4 + (d & 3)] = zv;
    }
    __syncthreads();

    // ---- Phase B: cooperative K/V projection (e = t&31 owns one output channel) ----
    const int e  = t & 31;
    const int pg = t >> 5;               // 8 position groups
    float4 wkr[8], wvr[8];
    #pragma unroll
    for (int c = 0; c < 8; ++c) {
        wkr[c] = ((const float4*)(w_k + e * DCH))[c];
        wvr[c] = ((const float4*)(w_v + e * DCH))[c];
    }
    #pragma unroll 4
    for (int pass = 0; pass < HALO / 8; ++pass) {            // 40 passes
        int p = pass * 8 + pg;           // p&7 == pg (compile-friendly swizzle)
        float ka = 0.f, va = 0.f;
        #pragma unroll
        for (int c = 0; c < 8; ++c) {
            float4 z4 = ((const float4*)zs)[p * 8 + (c ^ pg)];
            ka += z4.x*wkr[c].x + z4.y*wkr[c].y + z4.z*wkr[c].z + z4.w*wkr[c].w;
            va += z4.x*wvr[c].x + z4.y*wvr[c].y + z4.z*wvr[c].z + z4.w*wvr[c].w;
        }
        int cp = (e >> 2) ^ pg;
        ks[p * DCH + cp * 4 + (e & 3)] = ka;
        vs[p * DCH + cp * 4 + (e & 3)] = va;
    }

    // ---- Phase B2: own-query Q projection (weights are wave-uniform -> s_loads) ----
    float4 z4r[8];
    {
        int p = t + WINR;
        int pm = p & 7;
        #pragma unroll
        for (int c = 0; c < 8; ++c)
            z4r[c] = ((const float4*)zs)[p * 8 + (c ^ pm)];
    }
    float q[DCH];
    #pragma unroll
    for (int e2 = 0; e2 < DCH; ++e2) {
        const float4* wq4 = (const float4*)(w_q + e2 * DCH);
        float acc = 0.f;
        #pragma unroll
        for (int c = 0; c < 8; ++c) {
            float4 wv4 = wq4[c];
            acc += z4r[c].x*wv4.x + z4r[c].y*wv4.y + z4r[c].z*wv4.z + z4r[c].w*wv4.w;
        }
        q[e2] = acc * 0.17677669529663688f;   // fold scale = 1/sqrt(32) into q
    }
    __syncthreads();

    // ---- Phase C+D: online-softmax banded attention, thread = query ----
    float m = -3.0e38f, l = 0.f;
    float o[DCH];
    #pragma unroll
    for (int d = 0; d < DCH; ++d) o[d] = 0.f;

    const int hq = h0 + t;               // global query position (always valid)
    #pragma unroll 2
    for (int off = 0; off <= 2 * WINR; ++off) {
        int p = t + off;                 // local key slot, in [0,320)
        int j = g0 + p;                  // global key position
        int pm = p & 7;
        bool valid = ((unsigned)j < H_DIM);
        float acc = 0.f;
        #pragma unroll
        for (int c = 0; c < 8; ++c) {
            float4 k4 = ((const float4*)ks)[p * 8 + (c ^ pm)];
            acc += q[4*c+0]*k4.x + q[4*c+1]*k4.y + q[4*c+2]*k4.z + q[4*c+3]*k4.w;
        }
        float mn   = valid ? fmaxf(m, acc) : m;
        float corr = __expf(m - mn);               // ==1 when m unchanged
        float pw   = valid ? __expf(acc - mn) : 0.f;
        l = l * corr + pw;
        m = mn;
        #pragma unroll
        for (int c = 0; c < 8; ++c) {
            float4 v4 = ((const float4*)vs)[p * 8 + (c ^ pm)];
            o[4*c+0] = o[4*c+0]*corr + pw*v4.x;
            o[4*c+1] = o[4*c+1]*corr + pw*v4.y;
            o[4*c+2] = o[4*c+2]*corr + pw*v4.z;
            o[4*c+3] = o[4*c+3]*corr + pw*v4.w;
        }
    }
    const float inv = 1.0f / l;

    // ---- Phase E: out_pre = feat + gamma*o, plus GN2 partial sums ----
    const float xq = xrow[hq];
    const float gamma = gammap[0];
    float so = 0.f, so2 = 0.f;
    float* op = out_pre + ((size_t)row * H_DIM + hq) * DCH;
    #pragma unroll
    for (int c = 0; c < 8; ++c) {
        float4 wi4 = ((const float4*)w_in)[c];
        float4 r;
        r.x = xq * wi4.x + gamma * (o[4*c+0] * inv);
        r.y = xq * wi4.y + gamma * (o[4*c+1] * inv);
        r.z = xq * wi4.z + gamma * (o[4*c+2] * inv);
        r.w = xq * wi4.w + gamma * (o[4*c+3] * inv);
        ((float4*)op)[c] = r;
        so  += r.x + r.y + r.z + r.w;
        so2 += r.x*r.x + r.y*r.y + r.z*r.z + r.w*r.w;
    }
    double ds = (double)so, ds2 = (double)so2;
    #pragma unroll
    for (int ofs = 32; ofs; ofs >>= 1) {
        ds  += __shfl_down(ds, ofs);
        ds2 += __shfl_down(ds2, ofs);
    }
    if ((t & 63) == 0) {
        atomicAdd(&gn2acc[batch*2 + 0], ds);
        atomicAdd(&gn2acc[batch*2 + 1], ds2);
    }
}

// ---------------------------------------------------------------- K4: GN2 + gelu + out-projection
__global__ __launch_bounds__(256) void k_out(
    const float* __restrict__ out_pre,
    const float* __restrict__ w_out,
    const float* __restrict__ gn_w,
    const float* __restrict__ gn_b,
    const double* __restrict__ acc,       // GN2 sums at [4..7]
    float* __restrict__ outp)
{
    const int pix = blockIdx.x * 256 + threadIdx.x;   // 0..131071
    const int batch = pix >> 16;
    const double n2 = 2097152.0;
    const double S  = acc[4 + batch*2];
    const double S2 = acc[5 + batch*2];
    const double mu = S / n2;
    const double var = S2 / n2 - mu * mu;
    const float muf  = (float)mu;
    const float rstd = (float)(1.0 / sqrt(var + 1e-5));

    const float4* ip = (const float4*)(out_pre + (size_t)pix * DCH);
    float acc_o = 0.f;
    #pragma unroll
    for (int c = 0; c < 8; ++c) {
        float4 v  = ip[c];
        float4 gw = ((const float4*)gn_w)[c];
        float4 gb = ((const float4*)gn_b)[c];
        float4 wo = ((const float4*)w_out)[c];
        acc_o += gelu_f((v.x - muf) * rstd * gw.x + gb.x) * wo.x;
        acc_o += gelu_f((v.y - muf) * rstd * gw.y + gb.y) * wo.y;
        acc_o += gelu_f((v.z - muf) * rstd * gw.z + gb.z) * wo.z;
        acc_o += gelu_f((v.w - muf) * rstd * gw.w + gb.w) * wo.w;
    }
    outp[pix] = acc_o;
}

// ---------------------------------------------------------------- launch
extern "C" void kernel_launch(void* const* d_in, const int* in_sizes, int n_in,
                              void* d_out, int out_size, void* d_ws, size_t ws_size,
                              hipStream_t stream) {
    const float* x     = (const float*)d_in[0];
    const float* w_in  = (const float*)d_in[1];
    const float* w_q   = (const float*)d_in[2];
    const float* w_k   = (const float*)d_in[3];
    const float* w_v   = (const float*)d_in[4];
    const float* w_out = (const float*)d_in[5];
    const float* gn_w  = (const float*)d_in[6];
    const float* gn_b  = (const float*)d_in[7];
    const float* gamma = (const float*)d_in[8];

    double* acc    = (double*)d_ws;                       // 8 doubles
    float* out_pre = (float*)((char*)d_ws + 256);         // 16.78 MB staging
    float* outp    = (float*)d_out;

    k_init  <<<dim3(1),   dim3(64),  0, stream>>>(acc);
    k_xstats<<<dim3(128), dim3(256), 0, stream>>>(x, acc);
    k_main  <<<dim3(NROW * (H_DIM / TQ)), dim3(256), 0, stream>>>(
        x, w_in, w_q, w_k, w_v, gn_w, gn_b, gamma, acc, acc + 4, out_pre);
    k_out   <<<dim3(512), dim3(256), 0, stream>>>(out_pre, w_out, gn_w, gn_b, acc, outp);
}